// Round 1
// baseline (2216.229 us; speedup 1.0000x reference)
//
#include <hip/hip_runtime.h>

#define E_    300
#define H2_   256
#define T_    10
#define B_    64
#define S_    256
#define G_    (S_*B_)     // 16384
#define GATES (4*H2_)     // 1024
#define KV    80          // whh columns cached in VGPRs per thread

// ---------------- prep: transpose whh -> whhT[d][k][r], bias sums ----------------
__global__ void prep_kernel(const float* __restrict__ whh_f, const float* __restrict__ whh_b,
                            const float* __restrict__ bih_f, const float* __restrict__ bhh_f,
                            const float* __restrict__ bih_b, const float* __restrict__ bhh_b,
                            float* __restrict__ whhT, float* __restrict__ bsum) {
    int idx = blockIdx.x * blockDim.x + threadIdx.x;
    int total = 2 * H2_ * GATES;               // 524288
    if (idx < total) {
        int d = idx >> 18;                     // / 262144
        int rem = idx & 262143;
        int k = rem >> 10;                     // hidden col
        int r = rem & 1023;                    // gate row
        const float* w = d ? whh_b : whh_f;    // (1024, 256) row-major
        whhT[idx] = w[r * H2_ + k];
    }
    if (idx < 2 * GATES) {
        int d = idx >> 10, j = idx & 1023;
        bsum[idx] = d ? (bih_b[j] + bhh_b[j]) : (bih_f[j] + bhh_f[j]);
    }
}

// ---------------- input projection GEMM: xp[d][g][j] = emb[tok[g]] . wih_d[j] + bsum ----------------
__global__ __launch_bounds__(256) void xproj_kernel(
    const int* __restrict__ sent, const float* __restrict__ emb,
    const float* __restrict__ wih_f, const float* __restrict__ wih_b,
    const float* __restrict__ bsum, float* __restrict__ xp) {
    __shared__ float As[128 * 21];   // padded rows (21) to break bank aliasing
    __shared__ float Bs[20 * 64];
    __shared__ int   toks[128];
    int gt = blockIdx.x, jt = blockIdx.y, d = blockIdx.z;
    const float* wih = d ? wih_b : wih_f;       // (1024, 300)
    int tid = threadIdx.x;
    int g0 = gt * 128, j0 = jt * 64;
    if (tid < 128) toks[tid] = sent[g0 + tid];
    __syncthreads();

    int ty = tid >> 4, tx = tid & 15;           // ty: 8-row group, tx: 4-col group
    float acc[8][4];
    float4 bv = *(const float4*)&bsum[d * 1024 + j0 + tx * 4];
    #pragma unroll
    for (int i = 0; i < 8; i++) { acc[i][0] = bv.x; acc[i][1] = bv.y; acc[i][2] = bv.z; acc[i][3] = bv.w; }

    for (int kt = 0; kt < 15; kt++) {
        int k0 = kt * 20;
        #pragma unroll
        for (int l = 0; l < 10; l++) {          // As: 128 rows x 20 k
            int e = l * 256 + tid; int i = e / 20, k = e % 20;
            As[i * 21 + k] = emb[(long)toks[i] * E_ + k0 + k];
        }
        #pragma unroll
        for (int l = 0; l < 5; l++) {           // Bs[k][j] = wih[j0+j][k0+k]
            int e = l * 256 + tid; int k = e >> 6, j = e & 63;
            Bs[k * 64 + j] = wih[(j0 + j) * E_ + k0 + k];
        }
        __syncthreads();
        #pragma unroll
        for (int k = 0; k < 20; k++) {
            float4 b4 = *(const float4*)&Bs[k * 64 + tx * 4];
            #pragma unroll
            for (int i = 0; i < 8; i++) {
                float a = As[(ty * 8 + i) * 21 + k];
                acc[i][0] += a * b4.x; acc[i][1] += a * b4.y;
                acc[i][2] += a * b4.z; acc[i][3] += a * b4.w;
            }
        }
        __syncthreads();
    }
    #pragma unroll
    for (int i = 0; i < 8; i++) {
        float4 o; o.x = acc[i][0]; o.y = acc[i][1]; o.z = acc[i][2]; o.w = acc[i][3];
        *(float4*)&xp[((long)d * G_ + g0 + ty * 8 + i) * 1024 + j0 + tx * 4] = o;
    }
}

// ---------------- LSTM: 128 independent WGs = (dir, batch); thread t owns gate-row t ----------------
__global__ __launch_bounds__(1024, 4) void lstm_kernel(
    const float* __restrict__ xp, const float* __restrict__ whhT,
    const float* __restrict__ h0, const float* __restrict__ c0,
    float* __restrict__ hcat) {
    __shared__ float4 h4buf[64];       // h_prev, 256 floats
    __shared__ float  g_lds[1024];     // gate preactivations
    float* h_lds = (float*)h4buf;
    int t = threadIdx.x;
    int d = blockIdx.x >> 6, b = blockIdx.x & 63;
    const float* wg  = whhT + (long)d * H2_ * GATES;   // [256][1024]
    const float* xpd = xp   + (long)d * G_ * 1024;

    float wreg[KV];
    #pragma unroll
    for (int k = 0; k < KV; k++) wreg[k] = wg[k * GATES + t];

    float c = 0.f;
    if (t < 256) {
        h_lds[t] = h0[d * B_ * H2_ + b * H2_ + t];
        c        = c0[d * B_ * H2_ + b * H2_ + t];
    }
    __syncthreads();

    for (int step = 0; step < S_; step++) {
        int s = d ? (S_ - 1 - step) : step;
        int g = s * B_ + b;
        float acc = xpd[(long)g * 1024 + t];
        #pragma unroll
        for (int k4 = 0; k4 < KV / 4; k4++) {            // VGPR-cached columns
            float4 h4 = h4buf[k4];
            acc += wreg[k4*4+0]*h4.x + wreg[k4*4+1]*h4.y
                 + wreg[k4*4+2]*h4.z + wreg[k4*4+3]*h4.w;
        }
        #pragma unroll 4
        for (int k4 = KV / 4; k4 < 64; k4++) {           // L2-streamed columns
            float4 h4 = h4buf[k4];
            float w0 = wg[(k4*4+0) * GATES + t];
            float w1 = wg[(k4*4+1) * GATES + t];
            float w2 = wg[(k4*4+2) * GATES + t];
            float w3 = wg[(k4*4+3) * GATES + t];
            acc += w0*h4.x + w1*h4.y + w2*h4.z + w3*h4.w;
        }
        g_lds[t] = acc;
        __syncthreads();
        if (t < 256) {
            float iv = g_lds[t],       fv = g_lds[256 + t];
            float gv = g_lds[512 + t], ov = g_lds[768 + t];
            float si = 1.f / (1.f + __expf(-iv));
            float sf = 1.f / (1.f + __expf(-fv));
            float so = 1.f / (1.f + __expf(-ov));
            float tg = tanhf(gv);
            c = sf * c + si * tg;
            float h = so * tanhf(c);
            h_lds[t] = h;
            hcat[(long)g * 512 + d * 256 + t] = h;
        }
        __syncthreads();
    }
}

// ---------------- feats: feats[g][tt] = hcat[g] . W_out[tt] + b_out[tt] ----------------
__global__ void feats_kernel(const float* __restrict__ hcat, const float* __restrict__ Wout,
                             const float* __restrict__ bout, float* __restrict__ feats) {
    int tid = threadIdx.x; int w = tid >> 6, l = tid & 63;
    int g = blockIdx.x * 4 + w;
    float r[8];
    #pragma unroll
    for (int m = 0; m < 8; m++) r[m] = hcat[(long)g * 512 + m * 64 + l];
    #pragma unroll
    for (int tt = 0; tt < 10; tt++) {
        float a = 0.f;
        #pragma unroll
        for (int m = 0; m < 8; m++) a += r[m] * Wout[tt * 512 + m * 64 + l];
        #pragma unroll
        for (int off = 32; off > 0; off >>= 1) a += __shfl_down(a, off);
        if (l == 0) feats[g * 10 + tt] = a + bout[tt];
    }
}

// ---------------- Viterbi: one block (1 wave) per original batch row ----------------
__global__ void viterbi_kernel(const float* __restrict__ feats, const float* __restrict__ trans,
                               float* __restrict__ out) {
    __shared__ unsigned char bp[256 * 16];
    int l = threadIdx.x; int b = blockIdx.x;
    float trrow[10];
    #pragma unroll
    for (int p = 0; p < 10; p++) trrow[p] = (l < 10) ? trans[l * 10 + p] : 0.f;
    float tr_stop = (l < 10) ? trans[90 + l] : -3e38f;
    float fv = (l == 8) ? 0.f : -10000.f;

    for (int s = 0; s < 256; s++) {
        float m = -3e38f; int arg = 0;
        #pragma unroll
        for (int p = 0; p < 10; p++) {         // ascending p + strict '>' == np.argmax tie-break
            float v = __shfl(fv, p) + trrow[p];
            if (v > m) { m = v; arg = p; }
        }
        float ft = (l < 10) ? feats[((long)b * 256 + s) * 10 + l] : 0.f;
        fv = m + ft;
        if (l < 10) bp[s * 16 + l] = (unsigned char)arg;
    }
    __syncthreads();
    float term = fv + tr_stop;
    float best = -3e38f; int bt = 0;
    #pragma unroll
    for (int p = 0; p < 10; p++) {
        float v = __shfl(term, p);
        if (v > best) { best = v; bt = p; }
    }
    if (l == 0) {
        out[b] = best;                          // path_score (B,1)
        int cur = bt;
        out[64 + b * 256 + 255] = (float)cur;   // path (B,S) as float tags
        for (int s = 254; s >= 0; s--) {
            cur = bp[(s + 1) * 16 + cur];
            out[64 + b * 256 + s] = (float)cur;
        }
    }
}

extern "C" void kernel_launch(void* const* d_in, const int* in_sizes, int n_in,
                              void* d_out, int out_size, void* d_ws, size_t ws_size,
                              hipStream_t stream) {
    const int*   sent  = (const int*)  d_in[0];
    const float* emb   = (const float*)d_in[1];
    const float* wih_f = (const float*)d_in[2];
    const float* whh_f = (const float*)d_in[3];
    const float* bih_f = (const float*)d_in[4];
    const float* bhh_f = (const float*)d_in[5];
    const float* wih_b = (const float*)d_in[6];
    const float* whh_b = (const float*)d_in[7];
    const float* bih_b = (const float*)d_in[8];
    const float* bhh_b = (const float*)d_in[9];
    const float* Wout  = (const float*)d_in[10];
    const float* bout  = (const float*)d_in[11];
    const float* h0    = (const float*)d_in[12];
    const float* c0    = (const float*)d_in[13];
    const float* trans = (const float*)d_in[14];

    float* ws    = (float*)d_ws;
    float* xp    = ws;                  // [2][16384][1024] = 33,554,432 floats
    float* hcat  = ws + 33554432;       // [16384][512]     =  8,388,608
    float* whhT  = ws + 41943040;       // [2][256][1024]   =    524,288
    float* bsum  = ws + 42467328;       // [2][1024]        =      2,048
    float* feats = ws + 42469376;       // [16384][10]      =    163,840
    float* out   = (float*)d_out;

    hipLaunchKernelGGL(prep_kernel, dim3(2048), dim3(256), 0, stream,
                       whh_f, whh_b, bih_f, bhh_f, bih_b, bhh_b, whhT, bsum);
    hipLaunchKernelGGL(xproj_kernel, dim3(128, 16, 2), dim3(256), 0, stream,
                       sent, emb, wih_f, wih_b, bsum, xp);
    hipLaunchKernelGGL(lstm_kernel, dim3(128), dim3(1024), 0, stream,
                       xp, whhT, h0, c0, hcat);
    hipLaunchKernelGGL(feats_kernel, dim3(4096), dim3(256), 0, stream,
                       hcat, Wout, bout, feats);
    hipLaunchKernelGGL(viterbi_kernel, dim3(64), dim3(64), 0, stream,
                       feats, trans, out);
}

// Round 2
// 1519.448 us; speedup vs baseline: 1.4586x; 1.4586x over previous
//
#include <hip/hip_runtime.h>
#include <hip/hip_cooperative_groups.h>

namespace cg = cooperative_groups;

#define E_    300
#define H2_   256
#define T_    10
#define B_    64
#define S_    256
#define G_    (S_*B_)     // 16384
#define GATES (4*H2_)     // 1024
#define KVR   192         // weight cols cached in VGPRs per thread
#define KLD   64          // weight cols cached in LDS per thread
#define WPITCH4 17        // float4 pitch for wlds (16 data + 1 pad -> bank spread)

// ---------------- prep: pack whh -> wpack[d][hf][k][t], bias sums ----------------
// wpack element [(d*2+hf)*256 + k][t]  (t in [0,512))  = whh_d[r][k],
// r = (t>>7)*256 + hf*128 + (t&127)   (thread t of half hf owns gate row r)
__global__ void prep_kernel(const float* __restrict__ whh_f, const float* __restrict__ whh_b,
                            const float* __restrict__ bih_f, const float* __restrict__ bhh_f,
                            const float* __restrict__ bih_b, const float* __restrict__ bhh_b,
                            float* __restrict__ wpack, float* __restrict__ bsum) {
    int idx = blockIdx.x * blockDim.x + threadIdx.x;
    if (idx < 2 * 2 * H2_ * 512) {             // 524288
        int dhf = idx >> 17;                   // 0..3
        int d = dhf >> 1, hf = dhf & 1;
        int rem = idx & 131071;
        int k = rem >> 9;                      // hidden col 0..255
        int t = rem & 511;
        int r = ((t >> 7) << 8) + hf * 128 + (t & 127);
        const float* w = d ? whh_b : whh_f;    // (1024, 256) row-major
        wpack[idx] = w[r * H2_ + k];
    }
    if (idx < 2 * GATES) {
        int d = idx >> 10, j = idx & 1023;
        bsum[idx] = d ? (bih_b[j] + bhh_b[j]) : (bih_f[j] + bhh_f[j]);
    }
}

// ---------------- input projection GEMM: xp[d][g][j] = emb[tok[g]] . wih_d[j] + bsum ----------------
__global__ __launch_bounds__(256) void xproj_kernel(
    const int* __restrict__ sent, const float* __restrict__ emb,
    const float* __restrict__ wih_f, const float* __restrict__ wih_b,
    const float* __restrict__ bsum, float* __restrict__ xp) {
    __shared__ float As[128 * 21];
    __shared__ float Bs[20 * 64];
    __shared__ int   toks[128];
    int gt = blockIdx.x, jt = blockIdx.y, d = blockIdx.z;
    const float* wih = d ? wih_b : wih_f;       // (1024, 300)
    int tid = threadIdx.x;
    int g0 = gt * 128, j0 = jt * 64;
    if (tid < 128) toks[tid] = sent[g0 + tid];
    __syncthreads();

    int ty = tid >> 4, tx = tid & 15;
    float acc[8][4];
    float4 bv = *(const float4*)&bsum[d * 1024 + j0 + tx * 4];
    #pragma unroll
    for (int i = 0; i < 8; i++) { acc[i][0] = bv.x; acc[i][1] = bv.y; acc[i][2] = bv.z; acc[i][3] = bv.w; }

    for (int kt = 0; kt < 15; kt++) {
        int k0 = kt * 20;
        #pragma unroll
        for (int l = 0; l < 10; l++) {
            int e = l * 256 + tid; int i = e / 20, k = e % 20;
            As[i * 21 + k] = emb[(long)toks[i] * E_ + k0 + k];
        }
        #pragma unroll
        for (int l = 0; l < 5; l++) {
            int e = l * 256 + tid; int k = e >> 6, j = e & 63;
            Bs[k * 64 + j] = wih[(j0 + j) * E_ + k0 + k];
        }
        __syncthreads();
        #pragma unroll
        for (int k = 0; k < 20; k++) {
            float4 b4 = *(const float4*)&Bs[k * 64 + tx * 4];
            #pragma unroll
            for (int i = 0; i < 8; i++) {
                float a = As[(ty * 8 + i) * 21 + k];
                acc[i][0] += a * b4.x; acc[i][1] += a * b4.y;
                acc[i][2] += a * b4.z; acc[i][3] += a * b4.w;
            }
        }
        __syncthreads();
    }
    #pragma unroll
    for (int i = 0; i < 8; i++) {
        float4 o; o.x = acc[i][0]; o.y = acc[i][1]; o.z = acc[i][2]; o.w = acc[i][3];
        *(float4*)&xp[((long)d * G_ + g0 + ty * 8 + i) * 1024 + j0 + tx * 4] = o;
    }
}

// ---------------- LSTM: 256 blocks = 128 (dir,batch) pairs x 2 halves ----------------
// Block (p,hf): 512 threads, thread t owns gate row r = (t>>7)*256 + hf*128 + (t&127).
// Weights register/LDS resident. Halves exchange 128 h-values/step via tagged u64 mailboxes.
__global__ __launch_bounds__(512, 2) void lstm_kernel(
    const float* __restrict__ xp, const float* __restrict__ wpack,
    const float* __restrict__ h0, const float* __restrict__ c0,
    float* __restrict__ hcat, unsigned long long* __restrict__ mbox) {
    __shared__ float  h_lds[256];
    __shared__ float  g_lds[512];
    __shared__ float4 wlds[512 * WPITCH4];   // 139264 B

    int t = threadIdx.x;
    int blk = blockIdx.x;
    int p = blk >> 1, hf = blk & 1;
    int d = p >> 6, b = p & 63;
    const float* wp = wpack + (long)((d * 2 + hf) * 256) * 512;

    // prologue: weights into VGPRs (pinned) and LDS
    float wreg[KVR];
    #pragma unroll
    for (int k = 0; k < KVR; k++) {
        wreg[k] = wp[(long)k * 512 + t];
        asm volatile("" : "+v"(wreg[k]));    // forbid re-materialization in the loop
    }
    #pragma unroll
    for (int k = KVR; k < 256; k += 4) {
        float4 wv;
        wv.x = wp[(long)(k + 0) * 512 + t];
        wv.y = wp[(long)(k + 1) * 512 + t];
        wv.z = wp[(long)(k + 2) * 512 + t];
        wv.w = wp[(long)(k + 3) * 512 + t];
        wlds[t * WPITCH4 + ((k - KVR) >> 2)] = wv;
    }
    cg::this_grid().sync();   // everyone done reading wpack -> mbox (aliasing it) is safe

    float c = 0.f;
    if (t < 256) h_lds[t] = h0[(d * B_ + b) * H2_ + t];
    if (t < 128) c = c0[(d * B_ + b) * H2_ + hf * 128 + t];
    __syncthreads();

    unsigned long long* mb_out = mbox + (size_t)((p * 2 + hf) * 2) * 128;
    unsigned long long* mb_in  = mbox + (size_t)((p * 2 + (1 - hf)) * 2) * 128;
    const long xbase = (long)d * G_ * 1024;
    const int  r = ((t >> 7) << 8) + hf * 128 + (t & 127);

    for (int step = 0; step < S_; step++) {
        int s = d ? (S_ - 1 - step) : step;
        int g = s * B_ + b;
        float acc = xp[xbase + (long)g * 1024 + r];
        const float4* h4 = (const float4*)h_lds;
        #pragma unroll
        for (int j = 0; j < KVR / 4; j++) {
            float4 hv = h4[j];
            acc += wreg[4*j+0] * hv.x + wreg[4*j+1] * hv.y
                 + wreg[4*j+2] * hv.z + wreg[4*j+3] * hv.w;
        }
        #pragma unroll
        for (int j = 0; j < KLD / 4; j++) {
            float4 wv = wlds[t * WPITCH4 + j];
            float4 hv = h4[KVR / 4 + j];
            acc += wv.x * hv.x + wv.y * hv.y + wv.z * hv.z + wv.w * hv.w;
        }
        g_lds[t] = acc;
        __syncthreads();
        if (t < 128) {
            float iv = g_lds[t],        fv = g_lds[128 + t];
            float gv = g_lds[256 + t],  ov = g_lds[384 + t];
            float si = 1.f / (1.f + __expf(-iv));
            float sf = 1.f / (1.f + __expf(-fv));
            float so = 1.f / (1.f + __expf(-ov));
            float tg = tanhf(gv);
            c = sf * c + si * tg;
            float h = so * tanhf(c);
            h_lds[hf * 128 + t] = h;
            union { float f; unsigned u; } cv; cv.f = h;
            __hip_atomic_store(&mb_out[(step & 1) * 128 + t],
                               ((unsigned long long)(unsigned)(step + 1) << 32) | cv.u,
                               __ATOMIC_RELAXED, __HIP_MEMORY_SCOPE_AGENT);
            hcat[(long)g * 512 + d * 256 + hf * 128 + t] = h;
        } else if (t < 256) {
            int u = t - 128;
            unsigned want = (unsigned)(step + 1);
            unsigned long long w;
            do {
                w = __hip_atomic_load(&mb_in[(step & 1) * 128 + u],
                                      __ATOMIC_RELAXED, __HIP_MEMORY_SCOPE_AGENT);
            } while ((unsigned)(w >> 32) != want);
            union { unsigned u32; float f; } cv; cv.u32 = (unsigned)w;
            h_lds[(1 - hf) * 128 + u] = cv.f;
        }
        __syncthreads();
    }
}

// ---------------- feats: feats[g][tt] = hcat[g] . W_out[tt] + b_out[tt] ----------------
__global__ void feats_kernel(const float* __restrict__ hcat, const float* __restrict__ Wout,
                             const float* __restrict__ bout, float* __restrict__ feats) {
    int tid = threadIdx.x; int w = tid >> 6, l = tid & 63;
    int g = blockIdx.x * 4 + w;
    float r[8];
    #pragma unroll
    for (int m = 0; m < 8; m++) r[m] = hcat[(long)g * 512 + m * 64 + l];
    #pragma unroll
    for (int tt = 0; tt < 10; tt++) {
        float a = 0.f;
        #pragma unroll
        for (int m = 0; m < 8; m++) a += r[m] * Wout[tt * 512 + m * 64 + l];
        #pragma unroll
        for (int off = 32; off > 0; off >>= 1) a += __shfl_down(a, off);
        if (l == 0) feats[g * 10 + tt] = a + bout[tt];
    }
}

// ---------------- Viterbi: one block (1 wave) per original batch row ----------------
__global__ void viterbi_kernel(const float* __restrict__ feats, const float* __restrict__ trans,
                               float* __restrict__ out) {
    __shared__ unsigned char bp[256 * 16];
    int l = threadIdx.x; int b = blockIdx.x;
    float trrow[10];
    #pragma unroll
    for (int p = 0; p < 10; p++) trrow[p] = (l < 10) ? trans[l * 10 + p] : 0.f;
    float tr_stop = (l < 10) ? trans[90 + l] : -3e38f;
    float fv = (l == 8) ? 0.f : -10000.f;

    for (int s = 0; s < 256; s++) {
        float m = -3e38f; int arg = 0;
        #pragma unroll
        for (int p = 0; p < 10; p++) {
            float v = __shfl(fv, p) + trrow[p];
            if (v > m) { m = v; arg = p; }
        }
        float ft = (l < 10) ? feats[((long)b * 256 + s) * 10 + l] : 0.f;
        fv = m + ft;
        if (l < 10) bp[s * 16 + l] = (unsigned char)arg;
    }
    __syncthreads();
    float term = fv + tr_stop;
    float best = -3e38f; int bt = 0;
    #pragma unroll
    for (int p = 0; p < 10; p++) {
        float v = __shfl(term, p);
        if (v > best) { best = v; bt = p; }
    }
    if (l == 0) {
        out[b] = best;
        int cur = bt;
        out[64 + b * 256 + 255] = (float)cur;
        for (int s = 254; s >= 0; s--) {
            cur = bp[(s + 1) * 16 + cur];
            out[64 + b * 256 + s] = (float)cur;
        }
    }
}

extern "C" void kernel_launch(void* const* d_in, const int* in_sizes, int n_in,
                              void* d_out, int out_size, void* d_ws, size_t ws_size,
                              hipStream_t stream) {
    const int*   sent  = (const int*)  d_in[0];
    const float* emb   = (const float*)d_in[1];
    const float* wih_f = (const float*)d_in[2];
    const float* whh_f = (const float*)d_in[3];
    const float* bih_f = (const float*)d_in[4];
    const float* bhh_f = (const float*)d_in[5];
    const float* wih_b = (const float*)d_in[6];
    const float* whh_b = (const float*)d_in[7];
    const float* bih_b = (const float*)d_in[8];
    const float* bhh_b = (const float*)d_in[9];
    const float* Wout  = (const float*)d_in[10];
    const float* bout  = (const float*)d_in[11];
    const float* h0    = (const float*)d_in[12];
    const float* c0    = (const float*)d_in[13];
    const float* trans = (const float*)d_in[14];

    float* ws    = (float*)d_ws;
    float* xp    = ws;                  // [2][16384][1024] = 33,554,432 floats
    float* hcat  = ws + 33554432;       // [16384][512]     =  8,388,608
    float* wpack = ws + 41943040;       // [2][2][256][512] =    524,288
    float* bsum  = ws + 42467328;       // [2][1024]        =      2,048
    float* feats = ws;                  // aliases xp (xp dead after lstm)
    unsigned long long* mbox = (unsigned long long*)(ws + 41943040); // aliases wpack (dead after grid.sync)
    float* out   = (float*)d_out;

    hipLaunchKernelGGL(prep_kernel, dim3(2048), dim3(256), 0, stream,
                       whh_f, whh_b, bih_f, bhh_f, bih_b, bhh_b, wpack, bsum);
    hipLaunchKernelGGL(xproj_kernel, dim3(128, 16, 2), dim3(256), 0, stream,
                       sent, emb, wih_f, wih_b, bsum, xp);

    void* lstm_args[] = { (void*)&xp, (void*)&wpack, (void*)&h0, (void*)&c0,
                          (void*)&hcat, (void*)&mbox };
    hipLaunchCooperativeKernel((const void*)lstm_kernel, dim3(256), dim3(512),
                               lstm_args, 0, stream);

    hipLaunchKernelGGL(feats_kernel, dim3(4096), dim3(256), 0, stream,
                       hcat, Wout, bout, feats);
    hipLaunchKernelGGL(viterbi_kernel, dim3(64), dim3(64), 0, stream,
                       feats, trans, out);
}